// Round 18
// baseline (417.272 us; speedup 1.0000x reference)
//
#include <hip/hip_runtime.h>

#define F 128
#define NB 4
#define NR 8
#define KPB 512           // keys per bucket (key = d*8+r)
#define BCAP 6144         // entries per bucket region (mean 5120, +14 sigma)
#define EPB 16384         // edges per pass1 block (1024 thr x 16 edges)
#define MAXBKT 784        // LDS capacity for bucket counters
#define CAPW 384          // LDS payload words per wave in accum

typedef __attribute__((ext_vector_type(8))) short bf16x8;
typedef __attribute__((ext_vector_type(4))) float f32x4;
typedef __attribute__((ext_vector_type(2))) float f32x2;
typedef unsigned long long u64;

__device__ __forceinline__ unsigned f2bf(float f) {  // RNE f32->bf16
    unsigned u = __float_as_uint(f);
    return (u + 0x7FFFu + ((u >> 16) & 1u)) >> 16;
}
__device__ __forceinline__ unsigned f2bf2(float lo, float hi) {
    return f2bf(lo) | (f2bf(hi) << 16);
}

// x f32 [N][128] -> xq[q][N][16 dwords] (quarter-sliced bf16 pairs):
// xq[((q*N)+n)*16+fl] packs features (q*32+2fl, q*32+2fl+1)
__global__ void cvt_xq_kernel(const float* __restrict__ x, unsigned* __restrict__ xq, int N) {
    int tid = blockIdx.x * blockDim.x + threadIdx.x;
    if (tid >= N * 64) return;
    int n = tid >> 6, p = tid & 63;
    int q = p >> 4, fl = p & 15;
    float lo = x[(size_t)n * 128 + p * 2];
    float hi = x[(size_t)n * 128 + p * 2 + 1];
    xq[((size_t)q * N + n) * 16 + fl] = f2bf2(lo, hi);
}

// Bt[o][b*128+k] = bf16(W_basis[b][k][o]) : [128][512]
__global__ void cvt_w_kernel(const float* __restrict__ Wb, unsigned short* __restrict__ Bt) {
    int t = blockIdx.x * blockDim.x + threadIdx.x;
    if (t >= F * NB * F) return;
    int o = t >> 9, bk = t & 511, b = bk >> 7, k = bk & 127;
    Bt[t] = (unsigned short)f2bf(Wb[((size_t)b * F + k) * F + o]);
}

// gcur[i] = i*BCAP (bucket region cursors)
__global__ void init_gcur(int* __restrict__ gcur, int nbkt) {
    int i = blockIdx.x * blockDim.x + threadIdx.x;
    if (i < nbkt) gcur[i] = i * BCAP;
}

// Pass 1: per-block LDS histogram over buckets -> one global atomic per
// (block,bucket) -> scatter 8B entries into reserved runs.
__global__ __launch_bounds__(1024) void bucket_scatter(const int* __restrict__ es,
                                                       const float* __restrict__ ev,
                                                       const int* __restrict__ ed,
                                                       int* __restrict__ gcur,
                                                       u64* __restrict__ bbuf,
                                                       int E, int nbkt) {
    __shared__ int lcnt[MAXBKT];
    __shared__ int lbase[MAXBKT];
    const int r = blockIdx.y;
    const int e0 = blockIdx.x * EPB;
    const int e1 = min(e0 + EPB, E);
    const size_t ebase = (size_t)r * E;
    const int t = threadIdx.x;
    const int bbuf_end = nbkt * BCAP - 1;

    for (int i = t; i < nbkt; i += 1024) lcnt[i] = 0;
    __syncthreads();

    int dd[16];
#pragma unroll
    for (int k = 0; k < 4; ++k) {
        int base = e0 + k * 4096 + t * 4;
        if (base + 4 <= e1) {
            int4 d4 = *(const int4*)&ed[ebase + base];
            dd[k * 4 + 0] = d4.x; dd[k * 4 + 1] = d4.y;
            dd[k * 4 + 2] = d4.z; dd[k * 4 + 3] = d4.w;
        } else {
#pragma unroll
            for (int u = 0; u < 4; ++u)
                dd[k * 4 + u] = (base + u < e1) ? ed[ebase + base + u] : -1;
        }
    }
#pragma unroll
    for (int k = 0; k < 16; ++k)
        if (dd[k] >= 0) atomicAdd(&lcnt[(dd[k] * NR + r) >> 9], 1);
    __syncthreads();

    for (int i = t; i < nbkt; i += 1024) {
        int c = lcnt[i];
        lbase[i] = c ? atomicAdd(&gcur[i], c) : 0;
        lcnt[i] = 0;
    }
    __syncthreads();

#pragma unroll
    for (int k = 0; k < 4; ++k) {
        int base = e0 + k * 4096 + t * 4;
        if (base + 4 <= e1) {
            int4 s4 = *(const int4*)&es[ebase + base];
            float4 v4 = *(const float4*)&ev[ebase + base];
            int ss[4] = {s4.x, s4.y, s4.z, s4.w};
            float vv[4] = {v4.x, v4.y, v4.z, v4.w};
#pragma unroll
            for (int u = 0; u < 4; ++u) {
                int key = dd[k * 4 + u] * NR + r;
                int b = key >> 9;
                int rk = atomicAdd(&lcnt[b], 1);
                int pos = min(lbase[b] + rk, bbuf_end);
                bbuf[pos] = (u64)((unsigned)(ss[u] & 0xFFFF) | ((unsigned)(key & 511) << 16))
                          | ((u64)(f2bf(vv[u]) << 16) << 32);
            }
        } else {
            for (int u = 0; u < 4; ++u) {
                if (base + u >= e1 || dd[k * 4 + u] < 0) continue;
                int key = dd[k * 4 + u] * NR + r;
                int b = key >> 9;
                int rk = atomicAdd(&lcnt[b], 1);
                int pos = min(lbase[b] + rk, bbuf_end);
                bbuf[pos] = (u64)((unsigned)(es[ebase + base + u] & 0xFFFF) | ((unsigned)(key & 511) << 16))
                          | ((u64)(f2bf(ev[ebase + base + u]) << 16) << 32);
            }
        }
    }
}

// bt[i] = bucket total
__global__ void bt_kernel(const int* __restrict__ gcur, int* __restrict__ bt, int nbkt) {
    int i = blockIdx.x * blockDim.x + threadIdx.x;
    if (i < nbkt) bt[i] = gcur[i] - i * BCAP;
}

// ---- coalesced 3-phase exclusive scan (over nbkt totals) ----
__global__ __launch_bounds__(512) void scan_reduce(const int* __restrict__ cnt,
                                                   int* __restrict__ bsum, int M) {
    int base = blockIdx.x * 4096 + threadIdx.x * 8;
    int s = 0;
    if (base + 8 <= M) {
        int4 a = *(const int4*)&cnt[base];
        int4 c = *(const int4*)&cnt[base + 4];
        s = a.x + a.y + a.z + a.w + c.x + c.y + c.z + c.w;
    } else {
        for (int i = base; i < M; ++i) s += cnt[i];
    }
    for (int off = 1; off < 64; off <<= 1) s += __shfl_xor(s, off);
    __shared__ int wsum[8];
    if ((threadIdx.x & 63) == 0) wsum[threadIdx.x >> 6] = s;
    __syncthreads();
    if (threadIdx.x == 0) {
        int t = 0;
#pragma unroll
        for (int k = 0; k < 8; ++k) t += wsum[k];
        bsum[blockIdx.x] = t;
    }
}

__global__ __launch_bounds__(1024) void scan_bsums(const int* __restrict__ bsum,
                                                   int* __restrict__ bbase, int nb) {
    __shared__ int sums[1024];
    int t = threadIdx.x;
    int v = (t < nb) ? bsum[t] : 0;
    sums[t] = v;
    __syncthreads();
    for (int d = 1; d < 1024; d <<= 1) {
        int u = (t >= d) ? sums[t - d] : 0;
        __syncthreads();
        sums[t] += u;
        __syncthreads();
    }
    if (t < nb) bbase[t] = sums[t] - v;
}

__global__ __launch_bounds__(512) void scan_write(const int* __restrict__ cnt,
                                                  const int* __restrict__ bbase,
                                                  int* __restrict__ offs, int M) {
    int t = threadIdx.x;
    int base = blockIdx.x * 4096 + t * 8;
    int ex[8];
    int s = 0;
    if (base + 8 <= M) {
        int4 a = *(const int4*)&cnt[base];
        int4 c = *(const int4*)&cnt[base + 4];
        int tmp[8] = {a.x, a.y, a.z, a.w, c.x, c.y, c.z, c.w};
#pragma unroll
        for (int k = 0; k < 8; ++k) { ex[k] = s; s += tmp[k]; }
    } else {
        for (int k = 0; k < 8; ++k) ex[k] = 0;
        int s2 = 0;
        for (int i = base, k = 0; i < M; ++i, ++k) { ex[k] = s2; s2 += cnt[i]; }
        s = s2;
    }
    __shared__ int sums[512];
    sums[t] = s;
    __syncthreads();
    for (int d = 1; d < 512; d <<= 1) {
        int u = (t >= d) ? sums[t - d] : 0;
        __syncthreads();
        sums[t] += u;
        __syncthreads();
    }
    int tb = bbase[blockIdx.x] + ((t == 0) ? 0 : sums[t - 1]);
    if (base + 8 <= M) {
        *(int4*)&offs[base] = make_int4(tb + ex[0], tb + ex[1], tb + ex[2], tb + ex[3]);
        *(int4*)&offs[base + 4] = make_int4(tb + ex[4], tb + ex[5], tb + ex[6], tb + ex[7]);
    } else {
        for (int i = base, k = 0; i < M; ++i, ++k) offs[i] = tb + ex[k];
    }
}

// Pass 2: one block per bucket. Stage the whole bucket into LDS ONCE,
// then hist + scan + scatter all from LDS -> dense 4B payload + segdesc.
__global__ __launch_bounds__(512) void densify(const u64* __restrict__ bbuf,
                                               const int* __restrict__ gcur,
                                               const int* __restrict__ boff,
                                               unsigned* __restrict__ payload,
                                               unsigned* __restrict__ segdesc, int M) {
    __shared__ unsigned slo[BCAP];
    __shared__ unsigned shi[BCAP];
    __shared__ int kcnt[KPB];
    __shared__ int koff[KPB];
    __shared__ int kcur[KPB];
    __shared__ int stmp[KPB];
    const int bk = blockIdx.x;
    const int start = bk * BCAP;
    const int cntE = min(gcur[bk] - start, BCAP);
    const int t = threadIdx.x;
    kcnt[t] = 0;
    kcur[t] = 0;
    __syncthreads();
    for (int i = t; i < cntE; i += 512) {
        u64 e = bbuf[start + i];
        unsigned elo = (unsigned)e;
        slo[i] = elo;
        shi[i] = (unsigned)(e >> 32);
        atomicAdd(&kcnt[(elo >> 16) & 511], 1);
    }
    __syncthreads();
    stmp[t] = kcnt[t];
    __syncthreads();
    for (int d = 1; d < KPB; d <<= 1) {
        int v = (t >= d) ? stmp[t - d] : 0;
        __syncthreads();
        stmp[t] += v;
        __syncthreads();
    }
    koff[t] = stmp[t] - kcnt[t];
    __syncthreads();
    const int gb = boff[bk];
    int key = bk * KPB + t;
    if (key < M)
        segdesc[key] = ((unsigned)(gb + koff[t]) << 8) | (unsigned)min(kcnt[t], 255);
    for (int i = t; i < cntE; i += 512) {
        unsigned elo = slo[i];
        int klo = (elo >> 16) & 511;
        int rk = atomicAdd(&kcur[klo], 1);
        payload[gb + koff[klo] + rk] = (elo & 0xFFFFu) | shi[i];
    }
}

// Quarter-sliced accum: one wave per dst; 4 lane-groups of 16 each handle
// one edge per step, gathering a 64B feature slice from the 3.2MB xq slice
// (L2-resident). Per-group segment tracking (divergent while-flush), cross-
// group shfl reduction at the end. Lanes of group 0 write the mix quarter.
__global__ __launch_bounds__(256) void accum_q(const unsigned* __restrict__ xq,
                                               const unsigned* __restrict__ payload,
                                               const unsigned* __restrict__ segdesc,
                                               const float* __restrict__ comp,
                                               unsigned* __restrict__ mix,
                                               int qoff, int c0, int c1) {
    __shared__ f32x4 scomp4[NR];
    __shared__ unsigned plds[4 * CAPW];
    if (threadIdx.x < NR) {
        float4 c = ((const float4*)comp)[threadIdx.x];
        scomp4[threadIdx.x] = (f32x4){c.x, c.y, c.z, c.w};
    }
    __syncthreads();
    const int wave = threadIdx.x >> 6, lane = threadIdx.x & 63;
    const int g = lane >> 4, fl = lane & 15;
    const int d = c0 + blockIdx.x * 4 + wave;
    if (d >= c1) return;

    uint4 sA = *(const uint4*)&segdesc[(size_t)d * 8];
    uint4 sB = *(const uint4*)&segdesc[(size_t)d * 8 + 4];
    unsigned s0 = (unsigned)__builtin_amdgcn_readfirstlane((int)sA.x);
    unsigned s1 = (unsigned)__builtin_amdgcn_readfirstlane((int)sA.y);
    unsigned s2 = (unsigned)__builtin_amdgcn_readfirstlane((int)sA.z);
    unsigned s3 = (unsigned)__builtin_amdgcn_readfirstlane((int)sA.w);
    unsigned s4 = (unsigned)__builtin_amdgcn_readfirstlane((int)sB.x);
    unsigned s5 = (unsigned)__builtin_amdgcn_readfirstlane((int)sB.y);
    unsigned s6 = (unsigned)__builtin_amdgcn_readfirstlane((int)sB.z);
    unsigned s7 = (unsigned)__builtin_amdgcn_readfirstlane((int)sB.w);
    const unsigned start = s0 >> 8;
    const int b0 = (int)((s1 >> 8) - start);
    const int b1 = (int)((s2 >> 8) - start);
    const int b2 = (int)((s3 >> 8) - start);
    const int b3 = (int)((s4 >> 8) - start);
    const int b4 = (int)((s5 >> 8) - start);
    const int b5 = (int)((s6 >> 8) - start);
    const int b6 = (int)((s7 >> 8) - start);
    const int b7 = (int)((s7 >> 8) - start + (s7 & 255u));
    const int total = b7;
    auto bval = [&](int c) {
        return c == 0 ? b0 : c == 1 ? b1 : c == 2 ? b2 : c == 3 ? b3
             : c == 4 ? b4 : c == 5 ? b5 : c == 6 ? b6 : b7;
    };

    const unsigned lbase = wave * CAPW;
    const int stg = min(total, CAPW);
    for (int o = lane; o < stg; o += 64)
        plds[lbase + o] = __builtin_nontemporal_load(&payload[start + o]);

    f32x2 a0 = {0.f, 0.f}, a1 = {0.f, 0.f}, a2 = {0.f, 0.f}, a3 = {0.f, 0.f};
    f32x2 sr = {0.f, 0.f};
    int cur = 0;            // per-lane (group-uniform) segment cursor
    int nb = bval(0);
    const int steps = (total + 3) >> 2;

    for (int sb = 0; sb < steps; sb += 4) {
        unsigned pw[4], gx[4];
#pragma unroll
        for (int k = 0; k < 4; ++k) {
            int idx = (sb + k) * 4 + g;
            bool valid = idx < total;
            unsigned p = 0;
            if (valid) p = (idx < CAPW) ? plds[lbase + idx] : payload[start + idx];
            pw[k] = p;
            gx[k] = valid ? xq[(size_t)(p & 0xFFFFu) * 16 + fl] : 0u;
        }
#pragma unroll
        for (int k = 0; k < 4; ++k) {
            int idx = (sb + k) * 4 + g;
            while (idx >= nb && cur < 7) {      // divergent, exec-masked
                f32x4 cw = scomp4[cur];
                a0 += sr * cw.x;
                a1 += sr * cw.y;
                a2 += sr * cw.z;
                a3 += sr * cw.w;
                sr = (f32x2){0.f, 0.f};
                ++cur;
                nb = bval(cur < 7 ? cur : 7);
            }
            float v = __uint_as_float(pw[k] & 0xFFFF0000u);
            f32x2 xv = {__uint_as_float(gx[k] << 16), __uint_as_float(gx[k] & 0xFFFF0000u)};
            sr += xv * v;
        }
    }
#pragma unroll
    for (int r = 0; r < 8; ++r) {
        if (cur < 8) {
            f32x4 cw = scomp4[cur];
            a0 += sr * cw.x;
            a1 += sr * cw.y;
            a2 += sr * cw.z;
            a3 += sr * cw.w;
            sr = (f32x2){0.f, 0.f};
            ++cur;
        }
    }
    // reduce across the 4 lane-groups (same features, different edges)
#pragma unroll
    for (int off = 16; off <= 32; off <<= 1) {
        a0.x += __shfl_xor(a0.x, off); a0.y += __shfl_xor(a0.y, off);
        a1.x += __shfl_xor(a1.x, off); a1.y += __shfl_xor(a1.y, off);
        a2.x += __shfl_xor(a2.x, off); a2.y += __shfl_xor(a2.y, off);
        a3.x += __shfl_xor(a3.x, off); a3.y += __shfl_xor(a3.y, off);
    }
    if (g == 0) {
        unsigned* mrow = mix + (size_t)(d - c0) * 256 + qoff + fl;
        mrow[0]   = f2bf2(a0.x, a0.y);
        mrow[64]  = f2bf2(a1.x, a1.y);
        mrow[128] = f2bf2(a2.x, a2.y);
        mrow[192] = f2bf2(a3.x, a3.y);
    }
}

// out[gbase+row][o] = relu( sum_K mix[row][K] * Bt[o][K] ), K=512.
__global__ __launch_bounds__(256) void gemm_mfma(const unsigned short* __restrict__ mix,
                                                 const unsigned short* __restrict__ Bt,
                                                 float* __restrict__ out,
                                                 int rows, int gbase, int N) {
    __shared__ unsigned short As[128 * 64];
    __shared__ unsigned short Bs[128 * 64];
    const int t = threadIdx.x;
    const int row0 = blockIdx.x * 128;
    const int w = t >> 6, lane = t & 63;
    f32x4 acc[2][8] = {};

    for (int kt = 0; kt < 8; ++kt) {
        __syncthreads();
        for (int u = t; u < 1024; u += 256) {
            int r = u >> 3, c = u & 7;
            int k8 = c * 8;
            int ks = k8 ^ ((r & 7) << 3);
            uint4 av = make_uint4(0, 0, 0, 0);
            if (row0 + r < rows) av = *(const uint4*)&mix[(size_t)(row0 + r) * 512 + kt * 64 + k8];
            *(uint4*)&As[r * 64 + ks] = av;
            uint4 bv = *(const uint4*)&Bt[(size_t)r * 512 + kt * 64 + k8];
            *(uint4*)&Bs[r * 64 + ks] = bv;
        }
        __syncthreads();
#pragma unroll
        for (int ks = 0; ks < 2; ++ks) {
            bf16x8 a[2], b[8];
            const int kbase = ks * 32 + (lane >> 4) * 8;
#pragma unroll
            for (int i = 0; i < 2; ++i) {
                int r = w * 32 + i * 16 + (lane & 15);
                int kk = kbase ^ ((r & 7) << 3);
                a[i] = *(bf16x8*)&As[r * 64 + kk];
            }
#pragma unroll
            for (int jj = 0; jj < 8; ++jj) {
                int o = jj * 16 + (lane & 15);
                int kk = kbase ^ ((o & 7) << 3);
                b[jj] = *(bf16x8*)&Bs[o * 64 + kk];
            }
#pragma unroll
            for (int i = 0; i < 2; ++i)
#pragma unroll
                for (int jj = 0; jj < 8; ++jj)
                    acc[i][jj] = __builtin_amdgcn_mfma_f32_16x16x32_bf16(a[i], b[jj], acc[i][jj], 0, 0, 0);
        }
    }

#pragma unroll
    for (int i = 0; i < 2; ++i) {
        int mbase = w * 32 + i * 16 + (lane >> 4) * 4;
#pragma unroll
        for (int q = 0; q < 4; ++q) {
            int m = mbase + q;
            int gr = gbase + row0 + m;
            if (row0 + m < rows && gr < N) {
#pragma unroll
                for (int jj = 0; jj < 8; ++jj) {
                    int n = jj * 16 + (lane & 15);
                    out[(size_t)gr * F + n] = fmaxf(acc[i][jj][q], 0.f);
                }
            }
        }
    }
}

extern "C" void kernel_launch(void* const* d_in, const int* in_sizes, int n_in,
                              void* d_out, int out_size, void* d_ws, size_t ws_size,
                              hipStream_t stream) {
    const float* x  = (const float*)d_in[0];
    const float* Wb = (const float*)d_in[1];
    const float* Wc = (const float*)d_in[2];
    const float* ev = (const float*)d_in[3];
    const int*   es = (const int*)d_in[4];
    const int*   ed = (const int*)d_in[5];
    float* out = (float*)d_out;

    const int N = in_sizes[0] / F;
    const int E = in_sizes[3] / NR;
    const int M = NR * N;                       // key space: d*8+r
    const int nbkt = (M + KPB - 1) / KPB;       // 782
    const int nb2 = (nbkt + 4095) / 4096;       // 1

    char* p = (char*)d_ws;
    auto alloc = [&](size_t bytes) -> char* {
        char* q = p;
        p += (bytes + 255) & ~(size_t)255;
        return q;
    };
    u64* bbuf          = (u64*)alloc((size_t)nbkt * BCAP * 8);        // 38.4 MB
    unsigned* payload  = (unsigned*)alloc((size_t)NR * E * 4);        // 16 MB
    int* gcur          = (int*)alloc((size_t)nbkt * 4);
    int* bt            = (int*)alloc((size_t)nbkt * 4);
    int* bsum          = (int*)alloc((size_t)(nb2 + 16) * 4);
    int* bbase         = (int*)alloc((size_t)(nb2 + 16) * 4);
    int* boff          = (int*)alloc((size_t)nbkt * 4);
    unsigned* segdesc  = (unsigned*)alloc((size_t)M * 4);             // 1.6 MB
    unsigned short* Bt = (unsigned short*)alloc((size_t)F * NB * F * 2);
    unsigned* xq       = (unsigned*)alloc((size_t)N * F * 2);         // 12.8 MB (4 slices)

    size_t used = (size_t)(p - (char*)d_ws);
    size_t rem = ws_size > used ? ws_size - used : (size_t)(128 * 1024);
    size_t mix_rows = (rem / (512 * 2)) & ~(size_t)127;
    int chunk = (int)(mix_rows < 128 ? 128
                      : (mix_rows > (size_t)N ? (size_t)((N + 127) & ~(size_t)127) : mix_rows));
    unsigned short* mixbuf = (unsigned short*)p;

    cvt_xq_kernel<<<(N * 64 + 255) / 256, 256, 0, stream>>>(x, xq, N);
    cvt_w_kernel<<<(F * NB * F + 255) / 256, 256, 0, stream>>>(Wb, Bt);
    init_gcur<<<(nbkt + 255) / 256, 256, 0, stream>>>(gcur, nbkt);

    dim3 bg((E + EPB - 1) / EPB, NR);
    bucket_scatter<<<bg, 1024, 0, stream>>>(es, ev, ed, gcur, bbuf, E, nbkt);

    bt_kernel<<<(nbkt + 255) / 256, 256, 0, stream>>>(gcur, bt, nbkt);
    scan_reduce<<<nb2, 512, 0, stream>>>(bt, bsum, nbkt);
    scan_bsums<<<1, 1024, 0, stream>>>(bsum, bbase, nb2);
    scan_write<<<nb2, 512, 0, stream>>>(bt, bbase, boff, nbkt);

    densify<<<nbkt, 512, 0, stream>>>(bbuf, gcur, boff, payload, segdesc, M);

    for (int c0 = 0; c0 < N; c0 += chunk) {
        int crows = min(chunk, N - c0);
        for (int q = 0; q < 4; ++q)
            accum_q<<<(crows + 3) / 4, 256, 0, stream>>>(
                xq + (size_t)q * N * 16, payload, segdesc, Wc,
                (unsigned*)mixbuf, q * 16, c0, c0 + crows);
        gemm_mfma<<<(crows + 127) / 128, 256, 0, stream>>>(mixbuf, Bt, out, crows, c0, N);
    }
}

// Round 19
// 211.797 us; speedup vs baseline: 1.9701x; 1.9701x over previous
//
#include <hip/hip_runtime.h>

#define F 128
#define NB 4
#define NR 8
#define KPB 512           // keys per bucket (key = d*8+r)
#define BCAP 6144         // entries per bucket region (mean 5120, +14 sigma)
#define EPB 8192          // edges per pass1 block (512 thr x 16 edges)
#define MAXBKT 784        // LDS capacity for bucket counters
#define CAPW 384          // LDS payload words per wave in accum

typedef __attribute__((ext_vector_type(8))) short bf16x8;
typedef __attribute__((ext_vector_type(4))) float f32x4;
typedef __attribute__((ext_vector_type(2))) float f32x2;
typedef unsigned long long u64;

__device__ __forceinline__ unsigned f2bf(float f) {  // RNE f32->bf16
    unsigned u = __float_as_uint(f);
    return (u + 0x7FFFu + ((u >> 16) & 1u)) >> 16;
}
__device__ __forceinline__ unsigned f2bf2(float lo, float hi) {
    return f2bf(lo) | (f2bf(hi) << 16);
}

// x f32 [N*128] -> bf16, 8 elems/thread
__global__ void cvt_x_kernel(const float4* __restrict__ x4, uint4* __restrict__ xb, int total8) {
    int i = blockIdx.x * blockDim.x + threadIdx.x;
    if (i >= total8) return;
    float4 a = x4[(size_t)i * 2], b = x4[(size_t)i * 2 + 1];
    xb[i] = make_uint4(f2bf2(a.x, a.y), f2bf2(a.z, a.w), f2bf2(b.x, b.y), f2bf2(b.z, b.w));
}

// Bt[o][b*128+k] = bf16(W_basis[b][k][o]) : [128][512]
__global__ void cvt_w_kernel(const float* __restrict__ Wb, unsigned short* __restrict__ Bt) {
    int t = blockIdx.x * blockDim.x + threadIdx.x;
    if (t >= F * NB * F) return;
    int o = t >> 9, bk = t & 511, b = bk >> 7, k = bk & 127;
    Bt[t] = (unsigned short)f2bf(Wb[((size_t)b * F + k) * F + o]);
}

// gcur[i] = i*BCAP (bucket region cursors)
__global__ void init_gcur(int* __restrict__ gcur, int nbkt) {
    int i = blockIdx.x * blockDim.x + threadIdx.x;
    if (i < nbkt) gcur[i] = i * BCAP;
}

// Pass 1: LDS histogram -> per-(block,bucket) global reservation -> LDS
// COUNTING SORT (entries bucket-sorted in LDS) -> coalesced run copy-out.
// entry: lo = src16 | klo9<<16 ; hi = valbf16<<16 | bucket_id(10b).
__global__ __launch_bounds__(512) void bucket_scatter(const int* __restrict__ es,
                                                      const float* __restrict__ ev,
                                                      const int* __restrict__ ed,
                                                      int* __restrict__ gcur,
                                                      u64* __restrict__ bbuf,
                                                      int E, int nbkt) {
    __shared__ u64 sorted[EPB];      // 64 KB
    __shared__ int lcnt[MAXBKT];
    __shared__ int lofs[MAXBKT];
    __shared__ int lbase[MAXBKT];
    __shared__ int stmp[512];
    const int r = blockIdx.y;
    const int e0 = blockIdx.x * EPB;
    const int e1 = min(e0 + EPB, E);
    const int cnt = e1 - e0;
    const size_t ebase = (size_t)r * E;
    const int t = threadIdx.x;
    const int bbuf_end = nbkt * BCAP - 1;

    for (int i = t; i < nbkt; i += 512) lcnt[i] = 0;
    __syncthreads();

    // load 16 edges/thread into regs (4 x int4 coalesced rounds)
    int dd[16], ss[16];
    float vv[16];
#pragma unroll
    for (int k = 0; k < 4; ++k) {
        int base = e0 + k * 2048 + t * 4;
        if (base + 4 <= e1) {
            int4 d4 = *(const int4*)&ed[ebase + base];
            int4 s4 = *(const int4*)&es[ebase + base];
            float4 v4 = *(const float4*)&ev[ebase + base];
            dd[k * 4 + 0] = d4.x; dd[k * 4 + 1] = d4.y; dd[k * 4 + 2] = d4.z; dd[k * 4 + 3] = d4.w;
            ss[k * 4 + 0] = s4.x; ss[k * 4 + 1] = s4.y; ss[k * 4 + 2] = s4.z; ss[k * 4 + 3] = s4.w;
            vv[k * 4 + 0] = v4.x; vv[k * 4 + 1] = v4.y; vv[k * 4 + 2] = v4.z; vv[k * 4 + 3] = v4.w;
        } else {
#pragma unroll
            for (int u = 0; u < 4; ++u) {
                int idx = base + u;
                bool ok = idx < e1;
                dd[k * 4 + u] = ok ? ed[ebase + idx] : -1;
                ss[k * 4 + u] = ok ? es[ebase + idx] : 0;
                vv[k * 4 + u] = ok ? ev[ebase + idx] : 0.f;
            }
        }
    }
#pragma unroll
    for (int k = 0; k < 16; ++k)
        if (dd[k] >= 0) atomicAdd(&lcnt[(dd[k] * NR + r) >> 9], 1);
    __syncthreads();

    // exclusive scan lcnt -> lofs (2 counters/thread + Hillis-Steele over 512)
    int c0v = (2 * t < nbkt) ? lcnt[2 * t] : 0;
    int c1v = (2 * t + 1 < nbkt) ? lcnt[2 * t + 1] : 0;
    stmp[t] = c0v + c1v;
    __syncthreads();
    for (int d = 1; d < 512; d <<= 1) {
        int v = (t >= d) ? stmp[t - d] : 0;
        __syncthreads();
        stmp[t] += v;
        __syncthreads();
    }
    int pre = (t == 0) ? 0 : stmp[t - 1];
    if (2 * t < nbkt) lofs[2 * t] = pre;
    if (2 * t + 1 < nbkt) lofs[2 * t + 1] = pre + c0v;
    // global reservations + reset lcnt to reuse as rank cursor
    for (int b = t; b < nbkt; b += 512) {
        int c = lcnt[b];
        lbase[b] = c ? atomicAdd(&gcur[b], c) : 0;
        lcnt[b] = 0;
    }
    __syncthreads();

    // counting-sort into LDS
#pragma unroll
    for (int k = 0; k < 16; ++k) {
        if (dd[k] < 0) continue;
        int key = dd[k] * NR + r;
        int b = key >> 9;
        int rk = atomicAdd(&lcnt[b], 1);
        sorted[lofs[b] + rk] = (u64)((unsigned)(ss[k] & 0xFFFF) | ((unsigned)(key & 511) << 16))
                             | ((u64)((f2bf(vv[k]) << 16) | (unsigned)b) << 32);
    }
    __syncthreads();

    // coalesced copy-out: consecutive lanes hit consecutive positions per run
    for (int i = t; i < cnt; i += 512) {
        u64 e = sorted[i];
        int bid = (int)((unsigned)(e >> 32) & 0x3FFu);
        int tgt = min(lbase[bid] + (i - lofs[bid]), bbuf_end);
        bbuf[tgt] = e;
    }
}

// bt[i] = bucket total
__global__ void bt_kernel(const int* __restrict__ gcur, int* __restrict__ bt, int nbkt) {
    int i = blockIdx.x * blockDim.x + threadIdx.x;
    if (i < nbkt) bt[i] = gcur[i] - i * BCAP;
}

// ---- coalesced 3-phase exclusive scan (over nbkt totals) ----
__global__ __launch_bounds__(512) void scan_reduce(const int* __restrict__ cnt,
                                                   int* __restrict__ bsum, int M) {
    int base = blockIdx.x * 4096 + threadIdx.x * 8;
    int s = 0;
    if (base + 8 <= M) {
        int4 a = *(const int4*)&cnt[base];
        int4 c = *(const int4*)&cnt[base + 4];
        s = a.x + a.y + a.z + a.w + c.x + c.y + c.z + c.w;
    } else {
        for (int i = base; i < M; ++i) s += cnt[i];
    }
    for (int off = 1; off < 64; off <<= 1) s += __shfl_xor(s, off);
    __shared__ int wsum[8];
    if ((threadIdx.x & 63) == 0) wsum[threadIdx.x >> 6] = s;
    __syncthreads();
    if (threadIdx.x == 0) {
        int t = 0;
#pragma unroll
        for (int k = 0; k < 8; ++k) t += wsum[k];
        bsum[blockIdx.x] = t;
    }
}

__global__ __launch_bounds__(1024) void scan_bsums(const int* __restrict__ bsum,
                                                   int* __restrict__ bbase, int nb) {
    __shared__ int sums[1024];
    int t = threadIdx.x;
    int v = (t < nb) ? bsum[t] : 0;
    sums[t] = v;
    __syncthreads();
    for (int d = 1; d < 1024; d <<= 1) {
        int u = (t >= d) ? sums[t - d] : 0;
        __syncthreads();
        sums[t] += u;
        __syncthreads();
    }
    if (t < nb) bbase[t] = sums[t] - v;
}

__global__ __launch_bounds__(512) void scan_write(const int* __restrict__ cnt,
                                                  const int* __restrict__ bbase,
                                                  int* __restrict__ offs, int M) {
    int t = threadIdx.x;
    int base = blockIdx.x * 4096 + t * 8;
    int ex[8];
    int s = 0;
    if (base + 8 <= M) {
        int4 a = *(const int4*)&cnt[base];
        int4 c = *(const int4*)&cnt[base + 4];
        int tmp[8] = {a.x, a.y, a.z, a.w, c.x, c.y, c.z, c.w};
#pragma unroll
        for (int k = 0; k < 8; ++k) { ex[k] = s; s += tmp[k]; }
    } else {
        for (int k = 0; k < 8; ++k) ex[k] = 0;
        int s2 = 0;
        for (int i = base, k = 0; i < M; ++i, ++k) { ex[k] = s2; s2 += cnt[i]; }
        s = s2;
    }
    __shared__ int sums[512];
    sums[t] = s;
    __syncthreads();
    for (int d = 1; d < 512; d <<= 1) {
        int u = (t >= d) ? sums[t - d] : 0;
        __syncthreads();
        sums[t] += u;
        __syncthreads();
    }
    int tb = bbase[blockIdx.x] + ((t == 0) ? 0 : sums[t - 1]);
    if (base + 8 <= M) {
        *(int4*)&offs[base] = make_int4(tb + ex[0], tb + ex[1], tb + ex[2], tb + ex[3]);
        *(int4*)&offs[base + 4] = make_int4(tb + ex[4], tb + ex[5], tb + ex[6], tb + ex[7]);
    } else {
        for (int i = base, k = 0; i < M; ++i, ++k) offs[i] = tb + ex[k];
    }
}

// Pass 2: one block per bucket. Stage the whole bucket into LDS ONCE,
// then hist + scan + scatter all from LDS -> dense 4B payload + segdesc.
// (hi word's low 16 bits carry the bucket id -> mask it off.)
__global__ __launch_bounds__(512) void densify(const u64* __restrict__ bbuf,
                                               const int* __restrict__ gcur,
                                               const int* __restrict__ boff,
                                               unsigned* __restrict__ payload,
                                               unsigned* __restrict__ segdesc, int M) {
    __shared__ unsigned slo[BCAP];
    __shared__ unsigned shi[BCAP];
    __shared__ int kcnt[KPB];
    __shared__ int koff[KPB];
    __shared__ int kcur[KPB];
    __shared__ int stmp[KPB];
    const int bk = blockIdx.x;
    const int start = bk * BCAP;
    const int cntE = min(gcur[bk] - start, BCAP);
    const int t = threadIdx.x;
    kcnt[t] = 0;
    kcur[t] = 0;
    __syncthreads();
    for (int i = t; i < cntE; i += 512) {
        u64 e = bbuf[start + i];
        unsigned elo = (unsigned)e;
        slo[i] = elo;
        shi[i] = (unsigned)(e >> 32);
        atomicAdd(&kcnt[(elo >> 16) & 511], 1);
    }
    __syncthreads();
    stmp[t] = kcnt[t];
    __syncthreads();
    for (int d = 1; d < KPB; d <<= 1) {
        int v = (t >= d) ? stmp[t - d] : 0;
        __syncthreads();
        stmp[t] += v;
        __syncthreads();
    }
    koff[t] = stmp[t] - kcnt[t];
    __syncthreads();
    const int gb = boff[bk];
    int key = bk * KPB + t;
    if (key < M)
        segdesc[key] = ((unsigned)(gb + koff[t]) << 8) | (unsigned)min(kcnt[t], 255);
    for (int i = t; i < cntE; i += 512) {
        unsigned elo = slo[i];
        int klo = (elo >> 16) & 511;
        int rk = atomicAdd(&kcur[klo], 1);
        payload[gb + koff[klo] + rk] = (elo & 0xFFFFu) | (shi[i] & 0xFFFF0000u);
    }
}

// one wave per dst. Bulk-stage the dst's contiguous payload run into LDS,
// then one flat 8-deep gather loop; segment boundaries flush sr->a.
__global__ __launch_bounds__(256) void accum_kernel(const unsigned* __restrict__ xb,
                                                    const unsigned* __restrict__ payload,
                                                    const unsigned* __restrict__ segdesc,
                                                    const float* __restrict__ comp,
                                                    unsigned* __restrict__ mix,
                                                    int c0, int c1) {
    __shared__ float4 scomp[NR];
    __shared__ unsigned plds[4 * CAPW];
    if (threadIdx.x < NR) scomp[threadIdx.x] = ((const float4*)comp)[threadIdx.x];
    __syncthreads();
    int wave = threadIdx.x >> 6, lane = threadIdx.x & 63;
    int d = c0 + blockIdx.x * 4 + wave;
    if (d >= c1) return;

    uint4 sA = *(const uint4*)&segdesc[(size_t)d * 8];
    uint4 sB = *(const uint4*)&segdesc[(size_t)d * 8 + 4];
    unsigned s0 = (unsigned)__builtin_amdgcn_readfirstlane((int)sA.x);
    unsigned s1 = (unsigned)__builtin_amdgcn_readfirstlane((int)sA.y);
    unsigned s2 = (unsigned)__builtin_amdgcn_readfirstlane((int)sA.z);
    unsigned s3 = (unsigned)__builtin_amdgcn_readfirstlane((int)sA.w);
    unsigned s4 = (unsigned)__builtin_amdgcn_readfirstlane((int)sB.x);
    unsigned s5 = (unsigned)__builtin_amdgcn_readfirstlane((int)sB.y);
    unsigned s6 = (unsigned)__builtin_amdgcn_readfirstlane((int)sB.z);
    unsigned s7 = (unsigned)__builtin_amdgcn_readfirstlane((int)sB.w);
    const unsigned start = s0 >> 8;
    const int b0 = (int)((s1 >> 8) - start);
    const int b1 = (int)((s2 >> 8) - start);
    const int b2 = (int)((s3 >> 8) - start);
    const int b3 = (int)((s4 >> 8) - start);
    const int b4 = (int)((s5 >> 8) - start);
    const int b5 = (int)((s6 >> 8) - start);
    const int b6 = (int)((s7 >> 8) - start);
    const int b7 = (int)((s7 >> 8) - start + (s7 & 255u));
    const int total = b7;
    auto bval = [&](int c) {
        return c == 0 ? b0 : c == 1 ? b1 : c == 2 ? b2 : c == 3 ? b3
             : c == 4 ? b4 : c == 5 ? b5 : c == 6 ? b6 : b7;
    };

    const unsigned lbase = wave * CAPW;
    const int stg = min(total, CAPW);
    for (int o = lane; o < stg; o += 64)
        plds[lbase + o] = __builtin_nontemporal_load(&payload[start + o]);

    f32x2 a0 = {0.f, 0.f}, a1 = {0.f, 0.f}, a2 = {0.f, 0.f}, a3 = {0.f, 0.f};
    f32x2 sr = {0.f, 0.f};
    int cur = 0;
    int nb = bval(0);
    auto flush = [&]() {
        float4 cw = scomp[cur];
        a0 += sr * cw.x;
        a1 += sr * cw.y;
        a2 += sr * cw.z;
        a3 += sr * cw.w;
        sr = (f32x2){0.f, 0.f};
        ++cur;
        nb = bval(cur < 7 ? cur : 7);
    };

    int i = 0;
    for (; i + 8 <= total; i += 8) {
        unsigned pw[8];
        if (i + 8 <= CAPW) {
#pragma unroll
            for (int k = 0; k < 8; ++k)
                pw[k] = (unsigned)__builtin_amdgcn_readfirstlane((int)plds[lbase + i + k]);
        } else {
#pragma unroll
            for (int k = 0; k < 8; ++k)
                pw[k] = (unsigned)__builtin_amdgcn_readfirstlane((int)payload[start + i + k]);
        }
        unsigned g[8];
#pragma unroll
        for (int k = 0; k < 8; ++k)
            g[k] = xb[(size_t)(pw[k] & 0xFFFFu) * 64 + lane];
#pragma unroll
        for (int k = 0; k < 8; ++k) {
            while (i + k >= nb && cur < 7) flush();
            float v = __uint_as_float(pw[k] & 0xFFFF0000u);
            f32x2 xv = {__uint_as_float(g[k] << 16), __uint_as_float(g[k] & 0xFFFF0000u)};
            sr += xv * v;
        }
    }
    for (; i < total; ++i) {
        unsigned pw = (unsigned)__builtin_amdgcn_readfirstlane(
            (int)((i < CAPW) ? plds[lbase + i] : payload[start + i]));
        unsigned g = xb[(size_t)(pw & 0xFFFFu) * 64 + lane];
        while (i >= nb && cur < 7) flush();
        float v = __uint_as_float(pw & 0xFFFF0000u);
        f32x2 xv = {__uint_as_float(g << 16), __uint_as_float(g & 0xFFFF0000u)};
        sr += xv * v;
    }
    while (cur < 8) {
        float4 cw = scomp[cur];
        a0 += sr * cw.x;
        a1 += sr * cw.y;
        a2 += sr * cw.z;
        a3 += sr * cw.w;
        sr = (f32x2){0.f, 0.f};
        ++cur;
    }

    unsigned* mrow = mix + (size_t)(d - c0) * 256 + lane;
    mrow[0]   = f2bf2(a0.x, a0.y);
    mrow[64]  = f2bf2(a1.x, a1.y);
    mrow[128] = f2bf2(a2.x, a2.y);
    mrow[192] = f2bf2(a3.x, a3.y);
}

// out[gbase+row][o] = relu( sum_K mix[row][K] * Bt[o][K] ), K=512.
__global__ __launch_bounds__(256) void gemm_mfma(const unsigned short* __restrict__ mix,
                                                 const unsigned short* __restrict__ Bt,
                                                 float* __restrict__ out,
                                                 int rows, int gbase, int N) {
    __shared__ unsigned short As[128 * 64];
    __shared__ unsigned short Bs[128 * 64];
    const int t = threadIdx.x;
    const int row0 = blockIdx.x * 128;
    const int w = t >> 6, lane = t & 63;
    f32x4 acc[2][8] = {};

    for (int kt = 0; kt < 8; ++kt) {
        __syncthreads();
        for (int u = t; u < 1024; u += 256) {
            int r = u >> 3, c = u & 7;
            int k8 = c * 8;
            int ks = k8 ^ ((r & 7) << 3);
            uint4 av = make_uint4(0, 0, 0, 0);
            if (row0 + r < rows) av = *(const uint4*)&mix[(size_t)(row0 + r) * 512 + kt * 64 + k8];
            *(uint4*)&As[r * 64 + ks] = av;
            uint4 bv = *(const uint4*)&Bt[(size_t)r * 512 + kt * 64 + k8];
            *(uint4*)&Bs[r * 64 + ks] = bv;
        }
        __syncthreads();
#pragma unroll
        for (int ks = 0; ks < 2; ++ks) {
            bf16x8 a[2], b[8];
            const int kbase = ks * 32 + (lane >> 4) * 8;
#pragma unroll
            for (int i = 0; i < 2; ++i) {
                int r = w * 32 + i * 16 + (lane & 15);
                int kk = kbase ^ ((r & 7) << 3);
                a[i] = *(bf16x8*)&As[r * 64 + kk];
            }
#pragma unroll
            for (int jj = 0; jj < 8; ++jj) {
                int o = jj * 16 + (lane & 15);
                int kk = kbase ^ ((o & 7) << 3);
                b[jj] = *(bf16x8*)&Bs[o * 64 + kk];
            }
#pragma unroll
            for (int i = 0; i < 2; ++i)
#pragma unroll
                for (int jj = 0; jj < 8; ++jj)
                    acc[i][jj] = __builtin_amdgcn_mfma_f32_16x16x32_bf16(a[i], b[jj], acc[i][jj], 0, 0, 0);
        }
    }

#pragma unroll
    for (int i = 0; i < 2; ++i) {
        int mbase = w * 32 + i * 16 + (lane >> 4) * 4;
#pragma unroll
        for (int q = 0; q < 4; ++q) {
            int m = mbase + q;
            int gr = gbase + row0 + m;
            if (row0 + m < rows && gr < N) {
#pragma unroll
                for (int jj = 0; jj < 8; ++jj) {
                    int n = jj * 16 + (lane & 15);
                    out[(size_t)gr * F + n] = fmaxf(acc[i][jj][q], 0.f);
                }
            }
        }
    }
}

extern "C" void kernel_launch(void* const* d_in, const int* in_sizes, int n_in,
                              void* d_out, int out_size, void* d_ws, size_t ws_size,
                              hipStream_t stream) {
    const float* x  = (const float*)d_in[0];
    const float* Wb = (const float*)d_in[1];
    const float* Wc = (const float*)d_in[2];
    const float* ev = (const float*)d_in[3];
    const int*   es = (const int*)d_in[4];
    const int*   ed = (const int*)d_in[5];
    float* out = (float*)d_out;

    const int N = in_sizes[0] / F;
    const int E = in_sizes[3] / NR;
    const int M = NR * N;                       // key space: d*8+r
    const int nbkt = (M + KPB - 1) / KPB;       // 782
    const int nb2 = (nbkt + 4095) / 4096;       // 1

    char* p = (char*)d_ws;
    auto alloc = [&](size_t bytes) -> char* {
        char* q = p;
        p += (bytes + 255) & ~(size_t)255;
        return q;
    };
    u64* bbuf          = (u64*)alloc((size_t)nbkt * BCAP * 8);        // 38.4 MB
    unsigned* payload  = (unsigned*)alloc((size_t)NR * E * 4);        // 16 MB
    int* gcur          = (int*)alloc((size_t)nbkt * 4);
    int* bt            = (int*)alloc((size_t)nbkt * 4);
    int* bsum          = (int*)alloc((size_t)(nb2 + 16) * 4);
    int* bbase         = (int*)alloc((size_t)(nb2 + 16) * 4);
    int* boff          = (int*)alloc((size_t)nbkt * 4);
    unsigned* segdesc  = (unsigned*)alloc((size_t)M * 4);             // 1.6 MB
    unsigned short* Bt = (unsigned short*)alloc((size_t)F * NB * F * 2);
    unsigned* xb       = (unsigned*)alloc((size_t)N * F * 2);         // 12.8 MB

    size_t used = (size_t)(p - (char*)d_ws);
    size_t rem = ws_size > used ? ws_size - used : (size_t)(128 * 1024);
    size_t mix_rows = (rem / (512 * 2)) & ~(size_t)127;
    int chunk = (int)(mix_rows < 128 ? 128
                      : (mix_rows > (size_t)N ? (size_t)((N + 127) & ~(size_t)127) : mix_rows));
    unsigned short* mixbuf = (unsigned short*)p;

    cvt_x_kernel<<<(N * F / 8 + 255) / 256, 256, 0, stream>>>((const float4*)x, (uint4*)xb, N * F / 8);
    cvt_w_kernel<<<(F * NB * F + 255) / 256, 256, 0, stream>>>(Wb, Bt);
    init_gcur<<<(nbkt + 255) / 256, 256, 0, stream>>>(gcur, nbkt);

    dim3 bg((E + EPB - 1) / EPB, NR);
    bucket_scatter<<<bg, 512, 0, stream>>>(es, ev, ed, gcur, bbuf, E, nbkt);

    bt_kernel<<<(nbkt + 255) / 256, 256, 0, stream>>>(gcur, bt, nbkt);
    scan_reduce<<<nb2, 512, 0, stream>>>(bt, bsum, nbkt);
    scan_bsums<<<1, 1024, 0, stream>>>(bsum, bbase, nb2);
    scan_write<<<nb2, 512, 0, stream>>>(bt, bbase, boff, nbkt);

    densify<<<nbkt, 512, 0, stream>>>(bbuf, gcur, boff, payload, segdesc, M);

    for (int c0 = 0; c0 < N; c0 += chunk) {
        int crows = min(chunk, N - c0);
        accum_kernel<<<(crows + 3) / 4, 256, 0, stream>>>(xb, payload, segdesc, Wc,
                                                          (unsigned*)mixbuf, c0, c0 + crows);
        gemm_mfma<<<(crows + 127) / 128, 256, 0, stream>>>(mixbuf, Bt, out, crows, c0, N);
    }
}

// Round 20
// 201.829 us; speedup vs baseline: 2.0675x; 1.0494x over previous
//
#include <hip/hip_runtime.h>

#define F 128
#define NB 4
#define NR 8
#define KPB 512           // keys per bucket (key = d*8+r)
#define BCAP 6144         // entries per bucket region (mean 5120, +14 sigma)
#define EPB 8192          // edges per pass1 block (512 thr x 16 edges)
#define MAXBKT 784        // LDS capacity for bucket counters
#define CAPW 384          // LDS payload words per wave in accum

typedef __attribute__((ext_vector_type(8))) short bf16x8;
typedef __attribute__((ext_vector_type(4))) float f32x4;
typedef __attribute__((ext_vector_type(2))) float f32x2;
typedef unsigned long long u64;

__device__ __forceinline__ unsigned f2bf(float f) {  // RNE f32->bf16
    unsigned u = __float_as_uint(f);
    return (u + 0x7FFFu + ((u >> 16) & 1u)) >> 16;
}
__device__ __forceinline__ unsigned f2bf2(float lo, float hi) {
    return f2bf(lo) | (f2bf(hi) << 16);
}

// fused init: [0,A) cvt_x (8 f32 -> 8 bf16 per thread), [A,A+WT) cvt_w,
// [A+WT, A+WT+nbkt) init gcur.
__global__ void init_kernel(const float* __restrict__ x, unsigned* __restrict__ xb,
                            const float* __restrict__ Wb, unsigned short* __restrict__ Bt,
                            int* __restrict__ gcur, int A, int WT, int nbkt) {
    int id = blockIdx.x * blockDim.x + threadIdx.x;
    if (id < A) {
        const float4* x4 = (const float4*)x;
        float4 a = x4[(size_t)id * 2], b = x4[(size_t)id * 2 + 1];
        *(uint4*)&xb[(size_t)id * 4] =
            make_uint4(f2bf2(a.x, a.y), f2bf2(a.z, a.w), f2bf2(b.x, b.y), f2bf2(b.z, b.w));
    } else if (id < A + WT) {
        int t = id - A;
        int o = t >> 9, bk = t & 511, b = bk >> 7, k = bk & 127;
        Bt[t] = (unsigned short)f2bf(Wb[((size_t)b * F + k) * F + o]);
    } else if (id < A + WT + nbkt) {
        int i = id - A - WT;
        gcur[i] = i * BCAP;
    }
}

// Pass 1: LDS histogram -> per-(block,bucket) global reservation -> LDS
// COUNTING SORT -> coalesced run copy-out.
// entry: lo = src16 | klo9<<16 ; hi = valbf16<<16 | bucket_id(10b).
__global__ __launch_bounds__(512) void bucket_scatter(const int* __restrict__ es,
                                                      const float* __restrict__ ev,
                                                      const int* __restrict__ ed,
                                                      int* __restrict__ gcur,
                                                      u64* __restrict__ bbuf,
                                                      int E, int nbkt) {
    __shared__ u64 sorted[EPB];      // 64 KB
    __shared__ int lcnt[MAXBKT];
    __shared__ int lofs[MAXBKT];
    __shared__ int lbase[MAXBKT];
    __shared__ int stmp[512];
    const int r = blockIdx.y;
    const int e0 = blockIdx.x * EPB;
    const int e1 = min(e0 + EPB, E);
    const int cnt = e1 - e0;
    const size_t ebase = (size_t)r * E;
    const int t = threadIdx.x;
    const int bbuf_end = nbkt * BCAP - 1;

    for (int i = t; i < nbkt; i += 512) lcnt[i] = 0;
    __syncthreads();

    int dd[16], ss[16];
    float vv[16];
#pragma unroll
    for (int k = 0; k < 4; ++k) {
        int base = e0 + k * 2048 + t * 4;
        if (base + 4 <= e1) {
            int4 d4 = *(const int4*)&ed[ebase + base];
            int4 s4 = *(const int4*)&es[ebase + base];
            float4 v4 = *(const float4*)&ev[ebase + base];
            dd[k * 4 + 0] = d4.x; dd[k * 4 + 1] = d4.y; dd[k * 4 + 2] = d4.z; dd[k * 4 + 3] = d4.w;
            ss[k * 4 + 0] = s4.x; ss[k * 4 + 1] = s4.y; ss[k * 4 + 2] = s4.z; ss[k * 4 + 3] = s4.w;
            vv[k * 4 + 0] = v4.x; vv[k * 4 + 1] = v4.y; vv[k * 4 + 2] = v4.z; vv[k * 4 + 3] = v4.w;
        } else {
#pragma unroll
            for (int u = 0; u < 4; ++u) {
                int idx = base + u;
                bool ok = idx < e1;
                dd[k * 4 + u] = ok ? ed[ebase + idx] : -1;
                ss[k * 4 + u] = ok ? es[ebase + idx] : 0;
                vv[k * 4 + u] = ok ? ev[ebase + idx] : 0.f;
            }
        }
    }
#pragma unroll
    for (int k = 0; k < 16; ++k)
        if (dd[k] >= 0) atomicAdd(&lcnt[(dd[k] * NR + r) >> 9], 1);
    __syncthreads();

    int c0v = (2 * t < nbkt) ? lcnt[2 * t] : 0;
    int c1v = (2 * t + 1 < nbkt) ? lcnt[2 * t + 1] : 0;
    stmp[t] = c0v + c1v;
    __syncthreads();
    for (int d = 1; d < 512; d <<= 1) {
        int v = (t >= d) ? stmp[t - d] : 0;
        __syncthreads();
        stmp[t] += v;
        __syncthreads();
    }
    int pre = (t == 0) ? 0 : stmp[t - 1];
    if (2 * t < nbkt) lofs[2 * t] = pre;
    if (2 * t + 1 < nbkt) lofs[2 * t + 1] = pre + c0v;
    for (int b = t; b < nbkt; b += 512) {
        int c = lcnt[b];
        lbase[b] = c ? atomicAdd(&gcur[b], c) : 0;
        lcnt[b] = 0;
    }
    __syncthreads();

#pragma unroll
    for (int k = 0; k < 16; ++k) {
        if (dd[k] < 0) continue;
        int key = dd[k] * NR + r;
        int b = key >> 9;
        int rk = atomicAdd(&lcnt[b], 1);
        sorted[lofs[b] + rk] = (u64)((unsigned)(ss[k] & 0xFFFF) | ((unsigned)(key & 511) << 16))
                             | ((u64)((f2bf(vv[k]) << 16) | (unsigned)b) << 32);
    }
    __syncthreads();

    for (int i = t; i < cnt; i += 512) {
        u64 e = sorted[i];
        int bid = (int)((unsigned)(e >> 32) & 0x3FFu);
        int tgt = min(lbase[bid] + (i - lofs[bid]), bbuf_end);
        bbuf[tgt] = e;
    }
}

// fused bucket-total + exclusive scan over nbkt (<=1024) totals -> boff
__global__ __launch_bounds__(1024) void scan_kernel(const int* __restrict__ gcur,
                                                    int* __restrict__ boff, int nbkt) {
    __shared__ int sums[1024];
    int t = threadIdx.x;
    int v = (t < nbkt) ? (gcur[t] - t * BCAP) : 0;
    sums[t] = v;
    __syncthreads();
    for (int d = 1; d < 1024; d <<= 1) {
        int u = (t >= d) ? sums[t - d] : 0;
        __syncthreads();
        sums[t] += u;
        __syncthreads();
    }
    if (t < nbkt) boff[t] = sums[t] - v;
}

// Pass 2: one block per bucket. Stage the whole bucket into LDS ONCE,
// then hist + scan + scatter all from LDS -> dense 4B payload + segdesc.
__global__ __launch_bounds__(512) void densify(const u64* __restrict__ bbuf,
                                               const int* __restrict__ gcur,
                                               const int* __restrict__ boff,
                                               unsigned* __restrict__ payload,
                                               unsigned* __restrict__ segdesc, int M) {
    __shared__ unsigned slo[BCAP];
    __shared__ unsigned shi[BCAP];
    __shared__ int kcnt[KPB];
    __shared__ int koff[KPB];
    __shared__ int kcur[KPB];
    __shared__ int stmp[KPB];
    const int bk = blockIdx.x;
    const int start = bk * BCAP;
    const int cntE = min(gcur[bk] - start, BCAP);
    const int t = threadIdx.x;
    kcnt[t] = 0;
    kcur[t] = 0;
    __syncthreads();
    for (int i = t; i < cntE; i += 512) {
        u64 e = bbuf[start + i];
        unsigned elo = (unsigned)e;
        slo[i] = elo;
        shi[i] = (unsigned)(e >> 32);
        atomicAdd(&kcnt[(elo >> 16) & 511], 1);
    }
    __syncthreads();
    stmp[t] = kcnt[t];
    __syncthreads();
    for (int d = 1; d < KPB; d <<= 1) {
        int v = (t >= d) ? stmp[t - d] : 0;
        __syncthreads();
        stmp[t] += v;
        __syncthreads();
    }
    koff[t] = stmp[t] - kcnt[t];
    __syncthreads();
    const int gb = boff[bk];
    int key = bk * KPB + t;
    if (key < M)
        segdesc[key] = ((unsigned)(gb + koff[t]) << 8) | (unsigned)min(kcnt[t], 255);
    for (int i = t; i < cntE; i += 512) {
        unsigned elo = slo[i];
        int klo = (elo >> 16) & 511;
        int rk = atomicAdd(&kcur[klo], 1);
        payload[gb + koff[klo] + rk] = (elo & 0xFFFFu) | (shi[i] & 0xFFFF0000u);
    }
}

// one wave per dst. Bulk-stage the dst's contiguous payload run into LDS,
// then one flat 8-deep gather loop; segment boundaries flush sr->a.
__global__ __launch_bounds__(256) void accum_kernel(const unsigned* __restrict__ xb,
                                                    const unsigned* __restrict__ payload,
                                                    const unsigned* __restrict__ segdesc,
                                                    const float* __restrict__ comp,
                                                    unsigned* __restrict__ mix,
                                                    int c0, int c1) {
    __shared__ float4 scomp[NR];
    __shared__ unsigned plds[4 * CAPW];
    if (threadIdx.x < NR) scomp[threadIdx.x] = ((const float4*)comp)[threadIdx.x];
    __syncthreads();
    int wave = threadIdx.x >> 6, lane = threadIdx.x & 63;
    int d = c0 + blockIdx.x * 4 + wave;
    if (d >= c1) return;

    uint4 sA = *(const uint4*)&segdesc[(size_t)d * 8];
    uint4 sB = *(const uint4*)&segdesc[(size_t)d * 8 + 4];
    unsigned s0 = (unsigned)__builtin_amdgcn_readfirstlane((int)sA.x);
    unsigned s1 = (unsigned)__builtin_amdgcn_readfirstlane((int)sA.y);
    unsigned s2 = (unsigned)__builtin_amdgcn_readfirstlane((int)sA.z);
    unsigned s3 = (unsigned)__builtin_amdgcn_readfirstlane((int)sA.w);
    unsigned s4 = (unsigned)__builtin_amdgcn_readfirstlane((int)sB.x);
    unsigned s5 = (unsigned)__builtin_amdgcn_readfirstlane((int)sB.y);
    unsigned s6 = (unsigned)__builtin_amdgcn_readfirstlane((int)sB.z);
    unsigned s7 = (unsigned)__builtin_amdgcn_readfirstlane((int)sB.w);
    const unsigned start = s0 >> 8;
    const int b0 = (int)((s1 >> 8) - start);
    const int b1 = (int)((s2 >> 8) - start);
    const int b2 = (int)((s3 >> 8) - start);
    const int b3 = (int)((s4 >> 8) - start);
    const int b4 = (int)((s5 >> 8) - start);
    const int b5 = (int)((s6 >> 8) - start);
    const int b6 = (int)((s7 >> 8) - start);
    const int b7 = (int)((s7 >> 8) - start + (s7 & 255u));
    const int total = b7;
    auto bval = [&](int c) {
        return c == 0 ? b0 : c == 1 ? b1 : c == 2 ? b2 : c == 3 ? b3
             : c == 4 ? b4 : c == 5 ? b5 : c == 6 ? b6 : b7;
    };

    const unsigned lbase = wave * CAPW;
    const int stg = min(total, CAPW);
    for (int o = lane; o < stg; o += 64)
        plds[lbase + o] = __builtin_nontemporal_load(&payload[start + o]);

    f32x2 a0 = {0.f, 0.f}, a1 = {0.f, 0.f}, a2 = {0.f, 0.f}, a3 = {0.f, 0.f};
    f32x2 sr = {0.f, 0.f};
    int cur = 0;
    int nb = bval(0);
    auto flush = [&]() {
        float4 cw = scomp[cur];
        a0 += sr * cw.x;
        a1 += sr * cw.y;
        a2 += sr * cw.z;
        a3 += sr * cw.w;
        sr = (f32x2){0.f, 0.f};
        ++cur;
        nb = bval(cur < 7 ? cur : 7);
    };

    int i = 0;
    for (; i + 8 <= total; i += 8) {
        unsigned pw[8];
        if (i + 8 <= CAPW) {
#pragma unroll
            for (int k = 0; k < 8; ++k)
                pw[k] = (unsigned)__builtin_amdgcn_readfirstlane((int)plds[lbase + i + k]);
        } else {
#pragma unroll
            for (int k = 0; k < 8; ++k)
                pw[k] = (unsigned)__builtin_amdgcn_readfirstlane((int)payload[start + i + k]);
        }
        unsigned g[8];
#pragma unroll
        for (int k = 0; k < 8; ++k)
            g[k] = xb[(size_t)(pw[k] & 0xFFFFu) * 64 + lane];
#pragma unroll
        for (int k = 0; k < 8; ++k) {
            while (i + k >= nb && cur < 7) flush();
            float v = __uint_as_float(pw[k] & 0xFFFF0000u);
            f32x2 xv = {__uint_as_float(g[k] << 16), __uint_as_float(g[k] & 0xFFFF0000u)};
            sr += xv * v;
        }
    }
    for (; i < total; ++i) {
        unsigned pw = (unsigned)__builtin_amdgcn_readfirstlane(
            (int)((i < CAPW) ? plds[lbase + i] : payload[start + i]));
        unsigned g = xb[(size_t)(pw & 0xFFFFu) * 64 + lane];
        while (i >= nb && cur < 7) flush();
        float v = __uint_as_float(pw & 0xFFFF0000u);
        f32x2 xv = {__uint_as_float(g << 16), __uint_as_float(g & 0xFFFF0000u)};
        sr += xv * v;
    }
    while (cur < 8) {
        float4 cw = scomp[cur];
        a0 += sr * cw.x;
        a1 += sr * cw.y;
        a2 += sr * cw.z;
        a3 += sr * cw.w;
        sr = (f32x2){0.f, 0.f};
        ++cur;
    }

    unsigned* mrow = mix + (size_t)(d - c0) * 256 + lane;
    mrow[0]   = f2bf2(a0.x, a0.y);
    mrow[64]  = f2bf2(a1.x, a1.y);
    mrow[128] = f2bf2(a2.x, a2.y);
    mrow[192] = f2bf2(a3.x, a3.y);
}

// out[gbase+row][o] = relu( sum_K mix[row][K] * Bt[o][K] ), K=512.
__global__ __launch_bounds__(256) void gemm_mfma(const unsigned short* __restrict__ mix,
                                                 const unsigned short* __restrict__ Bt,
                                                 float* __restrict__ out,
                                                 int rows, int gbase, int N) {
    __shared__ unsigned short As[128 * 64];
    __shared__ unsigned short Bs[128 * 64];
    const int t = threadIdx.x;
    const int row0 = blockIdx.x * 128;
    const int w = t >> 6, lane = t & 63;
    f32x4 acc[2][8] = {};

    for (int kt = 0; kt < 8; ++kt) {
        __syncthreads();
        for (int u = t; u < 1024; u += 256) {
            int r = u >> 3, c = u & 7;
            int k8 = c * 8;
            int ks = k8 ^ ((r & 7) << 3);
            uint4 av = make_uint4(0, 0, 0, 0);
            if (row0 + r < rows) av = *(const uint4*)&mix[(size_t)(row0 + r) * 512 + kt * 64 + k8];
            *(uint4*)&As[r * 64 + ks] = av;
            uint4 bv = *(const uint4*)&Bt[(size_t)r * 512 + kt * 64 + k8];
            *(uint4*)&Bs[r * 64 + ks] = bv;
        }
        __syncthreads();
#pragma unroll
        for (int ks = 0; ks < 2; ++ks) {
            bf16x8 a[2], b[8];
            const int kbase = ks * 32 + (lane >> 4) * 8;
#pragma unroll
            for (int i = 0; i < 2; ++i) {
                int r = w * 32 + i * 16 + (lane & 15);
                int kk = kbase ^ ((r & 7) << 3);
                a[i] = *(bf16x8*)&As[r * 64 + kk];
            }
#pragma unroll
            for (int jj = 0; jj < 8; ++jj) {
                int o = jj * 16 + (lane & 15);
                int kk = kbase ^ ((o & 7) << 3);
                b[jj] = *(bf16x8*)&Bs[o * 64 + kk];
            }
#pragma unroll
            for (int i = 0; i < 2; ++i)
#pragma unroll
                for (int jj = 0; jj < 8; ++jj)
                    acc[i][jj] = __builtin_amdgcn_mfma_f32_16x16x32_bf16(a[i], b[jj], acc[i][jj], 0, 0, 0);
        }
    }

#pragma unroll
    for (int i = 0; i < 2; ++i) {
        int mbase = w * 32 + i * 16 + (lane >> 4) * 4;
#pragma unroll
        for (int q = 0; q < 4; ++q) {
            int m = mbase + q;
            int gr = gbase + row0 + m;
            if (row0 + m < rows && gr < N) {
#pragma unroll
                for (int jj = 0; jj < 8; ++jj) {
                    int n = jj * 16 + (lane & 15);
                    out[(size_t)gr * F + n] = fmaxf(acc[i][jj][q], 0.f);
                }
            }
        }
    }
}

extern "C" void kernel_launch(void* const* d_in, const int* in_sizes, int n_in,
                              void* d_out, int out_size, void* d_ws, size_t ws_size,
                              hipStream_t stream) {
    const float* x  = (const float*)d_in[0];
    const float* Wb = (const float*)d_in[1];
    const float* Wc = (const float*)d_in[2];
    const float* ev = (const float*)d_in[3];
    const int*   es = (const int*)d_in[4];
    const int*   ed = (const int*)d_in[5];
    float* out = (float*)d_out;

    const int N = in_sizes[0] / F;
    const int E = in_sizes[3] / NR;
    const int M = NR * N;                       // key space: d*8+r
    const int nbkt = (M + KPB - 1) / KPB;       // 782
    const int A = N * F / 8;                    // cvt_x threads
    const int WT = F * NB * F;                  // cvt_w threads

    char* p = (char*)d_ws;
    auto alloc = [&](size_t bytes) -> char* {
        char* q = p;
        p += (bytes + 255) & ~(size_t)255;
        return q;
    };
    u64* bbuf          = (u64*)alloc((size_t)nbkt * BCAP * 8);        // 38.4 MB
    unsigned* payload  = (unsigned*)alloc((size_t)NR * E * 4);        // 16 MB
    int* gcur          = (int*)alloc((size_t)nbkt * 4);
    int* boff          = (int*)alloc((size_t)nbkt * 4);
    unsigned* segdesc  = (unsigned*)alloc((size_t)M * 4);             // 1.6 MB
    unsigned short* Bt = (unsigned short*)alloc((size_t)F * NB * F * 2);
    unsigned* xb       = (unsigned*)alloc((size_t)N * F * 2);         // 12.8 MB

    size_t used = (size_t)(p - (char*)d_ws);
    size_t rem = ws_size > used ? ws_size - used : (size_t)(128 * 1024);
    size_t mix_rows = (rem / (512 * 2)) & ~(size_t)127;
    int chunk = (int)(mix_rows < 128 ? 128
                      : (mix_rows > (size_t)N ? (size_t)((N + 127) & ~(size_t)127) : mix_rows));
    unsigned short* mixbuf = (unsigned short*)p;

    init_kernel<<<(A + WT + nbkt + 255) / 256, 256, 0, stream>>>(x, xb, Wb, Bt, gcur, A, WT, nbkt);

    dim3 bg((E + EPB - 1) / EPB, NR);
    bucket_scatter<<<bg, 512, 0, stream>>>(es, ev, ed, gcur, bbuf, E, nbkt);

    scan_kernel<<<1, 1024, 0, stream>>>(gcur, boff, nbkt);

    densify<<<nbkt, 512, 0, stream>>>(bbuf, gcur, boff, payload, segdesc, M);

    for (int c0 = 0; c0 < N; c0 += chunk) {
        int crows = min(chunk, N - c0);
        accum_kernel<<<(crows + 3) / 4, 256, 0, stream>>>(xb, payload, segdesc, Wc,
                                                          (unsigned*)mixbuf, c0, c0 + crows);
        gemm_mfma<<<(crows + 127) / 128, 256, 0, stream>>>(mixbuf, Bt, out, crows, c0, N);
    }
}